// Round 10
// baseline (1089.506 us; speedup 1.0000x reference)
//
#include <hip/hip_runtime.h>
#include <hip/hip_bf16.h>

// Transformer block, B=2 T=2048 D=1024 H=16 DH=64 F=4096. fp32 in/out.
// R10: mgemm v4 (no A-LDS, pipelined B staging, 2 barriers/iter);
// fattn v2 (S^T layout -> in-thread softmax, vectorized P/O stores).
// Scratch: ws 8MB = Q -> O(in-place) -> F ; d_out 16MB = K,V -> P/Af,Hc -> out.

#define Bq_ 2
#define T_ 2048
#define D_ 1024
#define H_ 16
#define DH_ 64
#define F_ 4096
#define N_ (Bq_ * T_)   // 4096 rows
#define EPS_ 1e-5f
#define KP 72           // flash-attn LDS pitch (144B rows, 16B-aligned)

typedef __hip_bfloat16 bf16;
typedef unsigned short u16;
typedef __attribute__((ext_vector_type(8))) short bfrag;   // 8 bf16 = 4 VGPRs
typedef __attribute__((ext_vector_type(4))) float f32x4;

__device__ __forceinline__ u16 f2b(float f) {
    bf16 h = __float2bfloat16(f);
    return *(u16*)&h;
}
__device__ __forceinline__ float b2f_bits(u16 u) {
    return __uint_as_float(((unsigned)u) << 16);
}
__device__ __forceinline__ void unpack8(uint4 raw, float* f) {
    f[0] = __uint_as_float(raw.x << 16);
    f[1] = __uint_as_float(raw.x & 0xffff0000u);
    f[2] = __uint_as_float(raw.y << 16);
    f[3] = __uint_as_float(raw.y & 0xffff0000u);
    f[4] = __uint_as_float(raw.z << 16);
    f[5] = __uint_as_float(raw.z & 0xffff0000u);
    f[6] = __uint_as_float(raw.w << 16);
    f[7] = __uint_as_float(raw.w & 0xffff0000u);
}

// C(bf16 [.,1024]) = A[N_,1024] @ Bsub (+bias)(+relu)(+ACC). fp32 accum.
// A: AF32 ? fp32 : bf16; fragments read directly from global (no A-LDS).
// B fp32 global, staged->transposed->cvt in LDS, software-pipelined.
// QKV=0: B elem = B0f[(brow_off+k)*ldb + bcol_off + m]; C = C0.
// QKV=1: m in [0,3072): sel=m>>10 -> Wq/Wk/Wv [16,1024,64], mm=m&1023;
//        elem = W[((mm>>6)*1024+k)*64 + (mm&63)]; C = Csel col mm.
// Tile 128x128, BK=32; wave (wi,wj) owns 64x64 = 4x4 mfma 16x16x32.
template <int AF32, int QKV, int RELU, int ACC>
__global__ __launch_bounds__(256) void mgemm(
    const void* __restrict__ A,
    const float* __restrict__ B0f, const float* __restrict__ B1f, const float* __restrict__ B2f,
    u16* __restrict__ C0, u16* __restrict__ C1, u16* __restrict__ C2,
    int ldb, int brow_off, int bcol_off,
    const float* __restrict__ bias, int bias_off)
{
    __shared__ alignas(16) float Bs32[32][132];  // B fp32 staging
    __shared__ alignas(16) u16 Bt[128][40];      // B^T bf16, 80B rows

    const int tid = threadIdx.x;
    const int lane = tid & 63;
    const int w = tid >> 6;
    const int lo16 = lane & 15;
    const int quad = lane >> 4;
    const int wi = w >> 1, wj = w & 1;
    const int m0 = blockIdx.x * 128;
    const int n0 = blockIdx.y * 128;

    f32x4 acc[4][4] = {};

    const int bmq = tid & 31;            // B stage: col group (4 fp32)
    const int bkb = (tid >> 5) * 4;      // B stage: k base (4 rows)
    const int tm  = tid >> 1;            // transpose: m row
    const int tkh = (tid & 1) * 16;      // transpose: k half

    // B global base for this thread's column group (k-stride constant)
    const float* bbase;
    size_t bstride;
    if constexpr (QKV) {
        const int m = m0 + bmq * 4;
        const int sel = m >> 10;
        const int mm = m & 1023;
        const float* Wp = (sel == 0) ? B0f : ((sel == 1) ? B1f : B2f);
        bbase = Wp + (size_t)(mm >> 6) * 65536 + (mm & 63);
        bstride = 64;
    } else {
        bbase = B0f + (size_t)brow_off * ldb + bcol_off + m0 + bmq * 4;
        bstride = ldb;
    }

    // prologue: stage k0 = 0
    {
        float4 breg[4];
        #pragma unroll
        for (int kk = 0; kk < 4; kk++)
            breg[kk] = *(const float4*)(bbase + (size_t)(bkb + kk) * bstride);
        #pragma unroll
        for (int kk = 0; kk < 4; kk++)
            *(float4*)&Bs32[bkb + kk][bmq * 4] = breg[kk];
    }

    for (int k0 = 0; k0 < 1024; k0 += 32) {
        __syncthreads();   // Bs32 ready; Bt free (prev MFMA done)
        // transpose + cvt Bs32 -> Bt
        {
            u16 t[16];
            #pragma unroll
            for (int i = 0; i < 16; i++) t[i] = f2b(Bs32[tkh + i][tm]);
            *(uint4*)&Bt[tm][tkh] = *(uint4*)&t[0];
            *(uint4*)&Bt[tm][tkh + 8] = *(uint4*)&t[8];
        }
        __syncthreads();   // Bt ready; Bs32 free
        // prefetch next B tile (global -> regs), hidden under MFMA
        float4 breg[4];
        const int kn = k0 + 32;
        if (kn < 1024) {
            #pragma unroll
            for (int kk = 0; kk < 4; kk++)
                breg[kk] = *(const float4*)(bbase + (size_t)(kn + bkb + kk) * bstride);
        }
        // A fragments direct from global
        bfrag af[4];
        #pragma unroll
        for (int it = 0; it < 4; it++) {
            const size_t arow = (size_t)(n0 + wi * 64 + it * 16 + lo16) * 1024 + k0 + quad * 8;
            if constexpr (AF32) {
                const float* ap = (const float*)A + arow;
                float4 v0 = ((const float4*)ap)[0];
                float4 v1 = ((const float4*)ap)[1];
                u16 tt[8] = {f2b(v0.x), f2b(v0.y), f2b(v0.z), f2b(v0.w),
                             f2b(v1.x), f2b(v1.y), f2b(v1.z), f2b(v1.w)};
                af[it] = *(bfrag*)tt;
            } else {
                af[it] = *(const bfrag*)((const u16*)A + arow);
            }
        }
        // B fragments + MFMA
        bfrag bfv[4];
        #pragma unroll
        for (int jt = 0; jt < 4; jt++)
            bfv[jt] = *(const bfrag*)&Bt[wj * 64 + jt * 16 + lo16][quad * 8];
        #pragma unroll
        for (int it = 0; it < 4; it++)
            #pragma unroll
            for (int jt = 0; jt < 4; jt++)
                acc[it][jt] = __builtin_amdgcn_mfma_f32_16x16x32_bf16(
                    af[it], bfv[jt], acc[it][jt], 0, 0, 0);
        // write next B stage (Bs32 free since 2nd barrier)
        if (kn < 1024) {
            #pragma unroll
            for (int kk = 0; kk < 4; kk++)
                *(float4*)&Bs32[bkb + kk][bmq * 4] = breg[kk];
        }
    }
    // epilogue
    #pragma unroll
    for (int jt = 0; jt < 4; jt++) {
        const int col = m0 + wj * 64 + jt * 16 + lo16;
        u16* Cp;
        int cc;
        if constexpr (QKV) {
            const int sel = col >> 10;
            cc = col & 1023;
            Cp = (sel == 0) ? C0 : ((sel == 1) ? C1 : C2);
        } else {
            Cp = C0;
            cc = col;
        }
        const float bv = bias ? bias[bias_off + col] : 0.f;
        #pragma unroll
        for (int it = 0; it < 4; it++) {
            #pragma unroll
            for (int r = 0; r < 4; r++) {
                const int row = n0 + wi * 64 + it * 16 + quad * 4 + r;
                float v = acc[it][jt][r] + bv;
                if constexpr (RELU) v = fmaxf(v, 0.f);
                u16* cp = Cp + (size_t)row * 1024 + cc;
                if constexpr (ACC) v += b2f_bits(*cp);
                *cp = f2b(v);
            }
        }
    }
}

// Flash attention v2: one block per (b,h,q-tile 64). Computes S^T = K Q^T so
// softmax rows are (mostly) in-thread: each lane owns ONE q and a 16-value
// s-stripe; cross-s reduction = 15 in-thread + 2 xor-shuffles (quad dim).
// PV computed as O^T = V^T P. O written over Q in-place.
__global__ __launch_bounds__(256) void fattn_kernel(
    u16* __restrict__ Q, const u16* __restrict__ Kg, const u16* __restrict__ Vg)
{
    const int bi = blockIdx.x;
    const int qt = bi & 31;
    const int h  = (bi >> 5) & 15;
    const int b  = bi >> 9;
    const int tid = threadIdx.x;
    const int w = tid >> 6;
    const int lane = tid & 63;
    const int lo16 = lane & 15;
    const int quad = lane >> 4;

    __shared__ alignas(16) u16 Ks[64][KP];
    __shared__ alignas(16) u16 Vt[64][KP];      // Vt[e][s]
    __shared__ alignas(16) u16 Ps[4][16][KP];   // per-wave P[q_local][s]

    const int q0 = qt * 64;
    const int qg = q0 + w * 16 + lo16;          // this lane's query row
    const size_t qrow = (size_t)(b * T_ + qg) * 1024 + h * 64;
    bfrag qb0 = *(const bfrag*)(Q + qrow + quad * 8);        // B-op: Q[q][e]
    bfrag qb1 = *(const bfrag*)(Q + qrow + 32 + quad * 8);

    f32x4 oacc[4] = {};          // O^T: e = et*16+quad*4+r, col q = qg
    float m_s = -3e38f, l_s = 0.f;

    const int sr = tid >> 2;
    const int ec = (tid & 3) * 16;

    for (int st = 0; st <= qt; st++) {
        const int s0 = st * 64;
        // ---- stage K[s][e] and Vt[e][s] ----
        {
            const size_t grow = (size_t)(b * T_ + s0 + sr) * 1024 + h * 64 + ec;
            uint4 ka = *(const uint4*)(Kg + grow);
            uint4 kb2 = *(const uint4*)(Kg + grow + 8);
            *(uint4*)&Ks[sr][ec] = ka;
            *(uint4*)&Ks[sr][ec + 8] = kb2;
            uint4 va = *(const uint4*)(Vg + grow);
            uint4 vb2 = *(const uint4*)(Vg + grow + 8);
            unsigned vv[8] = {va.x, va.y, va.z, va.w, vb2.x, vb2.y, vb2.z, vb2.w};
            #pragma unroll
            for (int k2 = 0; k2 < 8; k2++) {
                Vt[ec + 2 * k2][sr]     = (u16)(vv[k2] & 0xffff);
                Vt[ec + 2 * k2 + 1][sr] = (u16)(vv[k2] >> 16);
            }
        }
        __syncthreads();

        // ---- S^T tiles: sv[nt][r] = S^T[s0+nt*16+quad*4+r][qg] ----
        float sv[4][4];
        #pragma unroll
        for (int nt = 0; nt < 4; nt++) {
            bfrag ka0 = *(const bfrag*)&Ks[nt * 16 + lo16][quad * 8];     // A-op: K[s][e]
            bfrag ka1 = *(const bfrag*)&Ks[nt * 16 + lo16][32 + quad * 8];
            f32x4 cs = {0.f, 0.f, 0.f, 0.f};
            cs = __builtin_amdgcn_mfma_f32_16x16x32_bf16(ka0, qb0, cs, 0, 0, 0);
            cs = __builtin_amdgcn_mfma_f32_16x16x32_bf16(ka1, qb1, cs, 0, 0, 0);
            #pragma unroll
            for (int r = 0; r < 4; r++) sv[nt][r] = cs[r] * 0.125f;
        }
        if (st == qt) {   // diagonal: mask s_local > q_local
            #pragma unroll
            for (int nt = 0; nt < 4; nt++)
                #pragma unroll
                for (int r = 0; r < 4; r++)
                    if (nt * 16 + quad * 4 + r > w * 16 + lo16) sv[nt][r] = -3e38f;
        }
        // ---- online softmax: one q per lane; reduce 16 in-thread + 2 shfl ----
        float mt = -3e38f;
        #pragma unroll
        for (int nt = 0; nt < 4; nt++)
            #pragma unroll
            for (int r = 0; r < 4; r++) mt = fmaxf(mt, sv[nt][r]);
        mt = fmaxf(mt, __shfl_xor(mt, 16, 64));
        mt = fmaxf(mt, __shfl_xor(mt, 32, 64));
        const float mnew = fmaxf(m_s, mt);
        const float alpha = __expf(m_s - mnew);
        m_s = mnew;
        float ssum = 0.f;
        #pragma unroll
        for (int nt = 0; nt < 4; nt++)
            #pragma unroll
            for (int r = 0; r < 4; r++) {
                sv[nt][r] = __expf(sv[nt][r] - mnew);
                ssum += sv[nt][r];
            }
        ssum += __shfl_xor(ssum, 16, 64);
        ssum += __shfl_xor(ssum, 32, 64);
        l_s = l_s * alpha + ssum;
        #pragma unroll
        for (int et = 0; et < 4; et++)
            #pragma unroll
            for (int r = 0; r < 4; r++) oacc[et][r] *= alpha;

        // ---- P -> LDS as P[q_local][s] (b64 stores), read back as B-op ----
        #pragma unroll
        for (int nt = 0; nt < 4; nt++) {
            uint2 pw;
            pw.x = (unsigned)f2b(sv[nt][0]) | ((unsigned)f2b(sv[nt][1]) << 16);
            pw.y = (unsigned)f2b(sv[nt][2]) | ((unsigned)f2b(sv[nt][3]) << 16);
            *(uint2*)&Ps[w][lo16][nt * 16 + quad * 4] = pw;
        }
        bfrag pb0 = *(const bfrag*)&Ps[w][lo16][quad * 8];
        bfrag pb1 = *(const bfrag*)&Ps[w][lo16][32 + quad * 8];
        // ---- O^T += V^T P ----
        #pragma unroll
        for (int et = 0; et < 4; et++) {
            bfrag va0 = *(const bfrag*)&Vt[et * 16 + lo16][quad * 8];
            bfrag va1 = *(const bfrag*)&Vt[et * 16 + lo16][32 + quad * 8];
            oacc[et] = __builtin_amdgcn_mfma_f32_16x16x32_bf16(va0, pb0, oacc[et], 0, 0, 0);
            oacc[et] = __builtin_amdgcn_mfma_f32_16x16x32_bf16(va1, pb1, oacc[et], 0, 0, 0);
        }
        __syncthreads();
    }
    // ---- epilogue: O[qg][e] = oacc/l, 4x8B stores to one global row ----
    const float rl = 1.f / l_s;
    u16* orow = Q + qrow;
    #pragma unroll
    for (int et = 0; et < 4; et++) {
        uint2 ow;
        ow.x = (unsigned)f2b(oacc[et][0] * rl) | ((unsigned)f2b(oacc[et][1] * rl) << 16);
        ow.y = (unsigned)f2b(oacc[et][2] * rl) | ((unsigned)f2b(oacc[et][3] * rl) << 16);
        *(uint2*)(orow + et * 16 + quad * 4) = ow;
    }
}

// LN(src bf16)*g + be + resid(fp32). WF32=1 -> fp32 dstf, else bf16 dstb.
template <int WF32>
__global__ __launch_bounds__(256) void ln_kernel(
    const u16* __restrict__ src, const float* __restrict__ resid,
    const float* __restrict__ g, const float* __restrict__ be,
    u16* __restrict__ dstb, float* __restrict__ dstf)
{
    const int r = blockIdx.x;
    const int tid = threadIdx.x;
    uint2 raw = ((const uint2*)(src + (size_t)r * D_))[tid];
    float y[4];
    y[0] = __uint_as_float(raw.x << 16);
    y[1] = __uint_as_float(raw.x & 0xffff0000u);
    y[2] = __uint_as_float(raw.y << 16);
    y[3] = __uint_as_float(raw.y & 0xffff0000u);
    float s = y[0] + y[1] + y[2] + y[3];
    float sq = y[0]*y[0] + y[1]*y[1] + y[2]*y[2] + y[3]*y[3];
    #pragma unroll
    for (int o = 32; o > 0; o >>= 1) {
        s += __shfl_down(s, o, 64);
        sq += __shfl_down(sq, o, 64);
    }
    __shared__ float rs[4], rq[4];
    if ((tid & 63) == 0) { rs[tid >> 6] = s; rq[tid >> 6] = sq; }
    __syncthreads();
    const float S = rs[0] + rs[1] + rs[2] + rs[3];
    const float Qm = rq[0] + rq[1] + rq[2] + rq[3];
    const float mu = S * (1.f / (float)D_);
    const float var = fmaxf(Qm * (1.f / (float)D_) - mu * mu, 0.f);
    const float rstd = rsqrtf(var + EPS_);
    const int c = tid * 4;
    #pragma unroll
    for (int i = 0; i < 4; i++) {
        y[i] = (y[i] - mu) * rstd * g[c + i] + be[c + i]
             + resid[(size_t)r * D_ + c + i];
    }
    if constexpr (WF32) {
        float4 o = {y[0], y[1], y[2], y[3]};
        ((float4*)(dstf + (size_t)r * D_))[tid] = o;
    } else {
        uint2 o;
        o.x = (unsigned)f2b(y[0]) | ((unsigned)f2b(y[1]) << 16);
        o.y = (unsigned)f2b(y[2]) | ((unsigned)f2b(y[3]) << 16);
        ((uint2*)(dstb + (size_t)r * D_))[tid] = o;
    }
}

extern "C" void kernel_launch(void* const* d_in, const int* in_sizes, int n_in,
                              void* d_out, int out_size, void* d_ws, size_t ws_size,
                              hipStream_t stream)
{
    const float* emb = (const float*)d_in[0];
    const float* Wq  = (const float*)d_in[1];
    const float* Wk  = (const float*)d_in[2];
    const float* Wv  = (const float*)d_in[3];
    const float* Wo  = (const float*)d_in[4];
    const float* bo  = (const float*)d_in[5];
    const float* W1  = (const float*)d_in[6];
    const float* b1  = (const float*)d_in[7];
    const float* W2  = (const float*)d_in[8];
    const float* b2  = (const float*)d_in[9];
    const float* g1  = (const float*)d_in[10];
    const float* be1 = (const float*)d_in[11];
    const float* g2  = (const float*)d_in[12];
    const float* be2 = (const float*)d_in[13];

    // ws 8MB: Q [N,1024] bf16 -> O (flash, in-place) -> F (FFN accum)
    // d_out 16MB: K [0,4M), V [4M,8M) -> P/Af [0,4M), Hc [4M,8M) -> fp32 out
    u16* WS = (u16*)d_ws;
    u16* DO = (u16*)d_out;
    u16* Q  = WS;
    u16* Kb = DO;
    u16* Vb = DO + (size_t)N_ * 1024;
    u16* O  = WS;
    u16* P  = DO;
    u16* Af = DO;
    u16* Hc = DO + (size_t)N_ * 1024;
    u16* F  = WS;
    float* outf = (float*)d_out;

    const dim3 blk(256);

    // 1) Q/K/V = emb @ {Wq,Wk,Wv}
    mgemm<1, 1, 0, 0><<<dim3(24, 32), blk, 0, stream>>>(
        emb, Wq, Wk, Wv, Q, Kb, Vb, 0, 0, 0, nullptr, 0);
    // 2) flash attention, O over Q
    fattn_kernel<<<Bq_ * H_ * (T_ / 64), blk, 0, stream>>>(Q, Kb, Vb);
    // 3) P = O @ Wo + bo  (over dead K)
    mgemm<0, 0, 0, 0><<<dim3(8, 32), blk, 0, stream>>>(
        O, Wo, nullptr, nullptr, P, nullptr, nullptr, 1024, 0, 0, bo, 0);
    // 4) Af = LN(P) + emb (in-place)
    ln_kernel<0><<<N_, blk, 0, stream>>>(P, emb, g1, be1, Af, nullptr);
    // 5-12) FFN in 4 hidden chunks of 1024
    for (int cch = 0; cch < 4; cch++) {
        mgemm<0, 0, 1, 0><<<dim3(8, 32), blk, 0, stream>>>(
            Af, W1, nullptr, nullptr, Hc, nullptr, nullptr,
            4096, 0, cch * 1024, b1, cch * 1024);
        if (cch == 0) {
            mgemm<0, 0, 0, 0><<<dim3(8, 32), blk, 0, stream>>>(
                Hc, W2, nullptr, nullptr, F, nullptr, nullptr,
                1024, 0, 0, b2, 0);
        } else {
            mgemm<0, 0, 0, 1><<<dim3(8, 32), blk, 0, stream>>>(
                Hc, W2, nullptr, nullptr, F, nullptr, nullptr,
                1024, cch * 1024, 0, nullptr, 0);
        }
    }
    // 13) out = fp32(LN(F) + emb)
    ln_kernel<1><<<N_, blk, 0, stream>>>(F, emb, g2, be2, nullptr, outf);
}